// Round 15
// baseline (892.419 us; speedup 1.0000x reference)
//
#include <hip/hip_runtime.h>

// ---------------------------------------------------------------------------
// Grid attention v16, bf16 MFMA 32x32x16 (gfx950). 4096 windows; n=49; D=512.
// = v15 (correct, 848us) + accumulator-ILP fix: every MFMA chain split
//   even/odd-ks into 2 (Q: aq0/aq1; KV: ak0/ak1/av0/av1; PV: oa0/oa1), summed
//   at the end. v15's single 32-deep dependent chain paid ~16cyc latency per
//   MFMA; split chains run at ~8cyc issue. VGPR 80 -> ~150 (2 waves/SIMD
//   budget is 256 -- free headroom).
// C-layout (m74/m101): col=lane&31, row=(reg&3)+8*(reg>>2)+4*(lane>>5).
// LDS = 141824: xb 50176 | yb 50176 | 4 pairs x 10368 (qb 3136|kb 3136|vt 4096)
// ws: W-frags [3][16h][32ks][64lane][8e] bf16 (1.5MB) + bias 512KB @1572864.
// ---------------------------------------------------------------------------

typedef __bf16 bf16x8 __attribute__((ext_vector_type(8)));
typedef __attribute__((ext_vector_type(4))) float f32x4;
typedef __attribute__((ext_vector_type(16))) float f32x16;

#define DEVI __device__ __forceinline__

DEVI unsigned short f2bf(float f) {  // round-to-nearest-even
  union { float f; unsigned u; } v; v.f = f;
  unsigned r = v.u + 0x7FFFu + ((v.u >> 16) & 1u);
  return (unsigned short)(r >> 16);
}
DEVI unsigned pkbf(float a, float b) {
  return (unsigned)f2bf(a) | ((unsigned)f2bf(b) << 16);
}

#define MFMA32(a, b, c) __builtin_amdgcn_mfma_f32_32x32x16_bf16((a), (b), (c), 0, 0, 0)

#define SWZ_Y(r)  ((((unsigned)(r)) & 7u) << 4)
#define SWZ_A(r)  (((((unsigned)(r)) >> 2) & 3u) << 5)
#define SWZ_P(r)  ((((unsigned)(r)) & 7u) << 4)
#define SWZ_VT(r) ((((unsigned)(r)) & 7u) << 4)

// ---------------- prep: weights -> 32x32x16 B-frags, bias -> sim^T layout ---
__global__ void prep_kernel(const float* __restrict__ Wq, const float* __restrict__ Wkv,
                            const float* __restrict__ bt, char* __restrict__ ws) {
  int t = blockIdx.x * 256 + threadIdx.x;
  if (t < 786432) {  // 3 * 16h * 32ks * 64lane * 8e
    int e = t & 7, lane = (t >> 3) & 63, ks = (t >> 9) & 31,
        h = (t >> 14) & 15, T = t >> 18;
    int row = ks * 16 + (lane >> 5) * 8 + e;   // K index in [0,512)
    int col = h * 32 + (lane & 31);            // N index (dh)
    float v;
    if (T == 0)      v = Wq[row * 512 + col] * 0.17677669529663687f;  // fold 1/sqrt(32)
    else if (T == 1) v = Wkv[row * 1024 + col];
    else             v = Wkv[row * 1024 + 512 + col];
    ((unsigned short*)ws)[t] = f2bf(v);
  }
  if (t < 65536) {  // 16h * 2it * 2jt * 64lane * 16reg f32, sim^T 32x32 C-layout
    int reg = t & 15, lane = (t >> 4) & 63, jt = (t >> 10) & 1, it = (t >> 11) & 1,
        h = (t >> 12) & 15;
    int i = it * 32 + (lane & 31);                                   // query col
    int j = jt * 32 + (reg & 3) + 8 * (reg >> 2) + 4 * (lane >> 5);  // key row
    float v;
    if (j >= 49)      v = -1e30f;   // mask padded key slots
    else if (i >= 49) v = 0.0f;     // padded query cols: keep finite
    else {
      int hi2 = i / 7, wi = i % 7, hj = j / 7, wj = j % 7;
      v = bt[((hi2 - hj + 6) * 13 + (wi - wj + 6)) * 16 + h];
    }
    ((float*)(ws + 1572864))[t] = v;
  }
}

// ---------------- LDS fragment loaders --------------------------------------
DEVI bf16x8 ldXY(const char* base, int row, int kc) {  // xb/yb [49][512]
  unsigned a = ((unsigned)(row * 1024 + kc * 2)) ^ SWZ_Y(row);
  return *(const bf16x8*)(base + a);
}
DEVI bf16x8 ldQK(const char* base, int row, int kc) {  // qb/kb [49][32]
  int rc = row < 48 ? row : 48;
  unsigned a = ((unsigned)(rc * 64 + kc * 2)) ^ SWZ_A(rc);
  return *(const bf16x8*)(base + a);
}
DEVI bf16x8 ldP2(const char* base, int row, int jc) {  // P [49][64]
  int rc = row < 48 ? row : 48;
  unsigned a = ((unsigned)(rc * 128 + jc * 2)) ^ SWZ_P(rc);
  return *(const bf16x8*)(base + a);
}
DEVI bf16x8 ldVT(const char* base, int dh, int jc) {   // vt [32][64]
  unsigned a = ((unsigned)(dh * 128 + jc * 2)) ^ SWZ_VT(dh);
  return *(const bf16x8*)(base + a);
}

// ---------------- main fused kernel ----------------------------------------
__global__ __launch_bounds__(512, 2)
void attn_kernel(const float* __restrict__ x, const float* __restrict__ y,
                 const char* __restrict__ wsW, const float* __restrict__ biasD,
                 float* __restrict__ out) {
  extern __shared__ char smem[];
  char* xb = smem;            // 50176
  char* yb = smem + 50176;    // 50176
  const int tid = threadIdx.x;
  const int lane = tid & 63, wave = tid >> 6;
  const int p = wave >> 1, sub = wave & 1;
  const int il = lane & 31, hi = lane >> 5;
  char* pbase = smem + 100352 + p * 10368;  // per-PAIR scratch
  char* qb = pbase;             // 3136
  char* kb = pbase + 3136;      // 3136
  char* vt = pbase + 6272;      // 4096
  char* Pb = pbase;             // P aliases qb+kb (6272B) -- barrier-guarded

  const int bw = blockIdx.x;
  const float* xs = x + (size_t)bw * 25088;
  const float* ys = y + (size_t)bw * 25088;

  // ---- stage x,y windows to LDS as bf16 ----
  for (int it = tid; it < 6272; it += 512) {
    float4 v = ((const float4*)xs)[it];
    float4 w = ((const float4*)ys)[it];
    int i = it >> 7;               // row 0..48
    int k = (it & 127) << 2;       // col 0..508
    unsigned a = ((unsigned)(i * 1024 + k * 2)) ^ SWZ_Y(i);
    uint2 ux, uy;
    ux.x = pkbf(v.x, v.y); ux.y = pkbf(v.z, v.w);
    uy.x = pkbf(w.x, w.y); uy.y = pkbf(w.z, w.w);
    *(uint2*)(xb + a) = ux;
    *(uint2*)(yb + a) = uy;
  }

  const bf16x8* wsQ = (const bf16x8*)wsW;                  // [h][ks][lane]
  const bf16x8* wsK = (const bf16x8*)(wsW + 524288);
  const bf16x8* wsV = (const bf16x8*)(wsW + 1048576);
  const float* bD = (const float*)biasD;                   // [h][it][jt][lane][16]
  const f32x16 fz16 = {0,0,0,0, 0,0,0,0, 0,0,0,0, 0,0,0,0};

  // A-frag token row for projections (M-split): wave sub owns rows sub*32..+31
  int arow = sub * 32 + il; if (arow > 48) arow = 48;      // clamp padding
  const int kfb = hi * 8;                                  // k-frag base

  for (int hh = 0; hh < 4; ++hh) {
    const int h = p * 4 + hh;

    __syncthreads();  // scratch free: partner's attn reads of prev head done

    // ---- Q-pass (32x32x16): 2 interleaved chains (even/odd ks) ----
    f32x16 aq0 = fz16, aq1 = fz16;
    {
      const bf16x8* pQ = wsQ + (size_t)(h * 32) * 64 + lane;
      bf16x8 qsr[8];
      #pragma unroll
      for (int i = 0; i < 8; ++i) qsr[i] = pQ[i * 64];
      #pragma unroll
      for (int ks = 0; ks < 32; ++ks) {
        bf16x8 bq = qsr[ks & 7];
        if (ks < 24) qsr[ks & 7] = pQ[(ks + 8) * 64];
        bf16x8 af = ldXY(xb, arow, ks * 16 + kfb);
        if (ks & 1) aq1 = MFMA32(af, bq, aq1);
        else        aq0 = MFMA32(af, bq, aq0);
      }
    }
    f32x16 aq;
    #pragma unroll
    for (int r = 0; r < 16; ++r) aq[r] = aq0[r] + aq1[r];
    // store q: [row][dh] u16 scatter; row = sub*32 + rq*8 + hi*4 + r2
    #pragma unroll
    for (int rq = 0; rq < 4; ++rq)
      #pragma unroll
      for (int r2 = 0; r2 < 4; ++r2) {
        int row = sub * 32 + rq * 8 + hi * 4 + r2;
        if (row < 49) {
          unsigned a = ((unsigned)(row * 64 + il * 2)) ^ SWZ_A(row);
          *(unsigned short*)(qb + a) = f2bf(aq[rq * 4 + r2]);
        }
      }

    // ---- KV-pass (32x32x16): 4 interleaved chains (K/V x even/odd ks) ----
    f32x16 ak0 = fz16, ak1 = fz16, av0 = fz16, av1 = fz16;
    {
      const bf16x8* pK = wsK + (size_t)(h * 32) * 64 + lane;
      const bf16x8* pV = wsV + (size_t)(h * 32) * 64 + lane;
      bf16x8 ksr[8], vsr[8];
      #pragma unroll
      for (int i = 0; i < 8; ++i) { ksr[i] = pK[i * 64]; vsr[i] = pV[i * 64]; }
      #pragma unroll
      for (int ks = 0; ks < 32; ++ks) {
        bf16x8 bk = ksr[ks & 7], bv = vsr[ks & 7];
        if (ks < 24) {
          ksr[ks & 7] = pK[(ks + 8) * 64];
          vsr[ks & 7] = pV[(ks + 8) * 64];
        }
        bf16x8 af = ldXY(yb, arow, ks * 16 + kfb);
        if (ks & 1) { ak1 = MFMA32(af, bk, ak1); av1 = MFMA32(af, bv, av1); }
        else        { ak0 = MFMA32(af, bk, ak0); av0 = MFMA32(af, bv, av0); }
      }
    }
    f32x16 ak, av;
    #pragma unroll
    for (int r = 0; r < 16; ++r) { ak[r] = ak0[r] + ak1[r]; av[r] = av0[r] + av1[r]; }
    // store k (u16 scatter) and vt ([dh][tok], packed uint2)
    #pragma unroll
    for (int rq = 0; rq < 4; ++rq) {
      #pragma unroll
      for (int r2 = 0; r2 < 4; ++r2) {
        int row = sub * 32 + rq * 8 + hi * 4 + r2;
        if (row < 49) {
          unsigned a = ((unsigned)(row * 64 + il * 2)) ^ SWZ_A(row);
          *(unsigned short*)(kb + a) = f2bf(ak[rq * 4 + r2]);
        }
      }
      int t0 = sub * 32 + rq * 8 + hi * 4;
      unsigned a = ((unsigned)(il * 128 + t0 * 2)) ^ SWZ_VT(il);
      uint2 pk;
      pk.x = pkbf(av[rq * 4 + 0], av[rq * 4 + 1]);
      pk.y = pkbf(av[rq * 4 + 2], av[rq * 4 + 3]);
      *(uint2*)(vt + a) = pk;
    }

    __syncthreads();  // q,k,vt visible to both waves of the pair

    // ======== attention (swapped QK^T, 32x32 tiles) ========
    // bias: [h][it=sub][jt][lane][16]
    f32x16 bias[2];
    #pragma unroll
    for (int jt = 0; jt < 2; ++jt) {
      const f32x4* bp = (const f32x4*)(bD + ((size_t)(((h * 2 + sub) * 2 + jt) * 64 + lane)) * 16);
      #pragma unroll
      for (int q4 = 0; q4 < 4; ++q4) {
        f32x4 b4 = bp[q4];
        bias[jt][q4 * 4 + 0] = b4[0]; bias[jt][q4 * 4 + 1] = b4[1];
        bias[jt][q4 * 4 + 2] = b4[2]; bias[jt][q4 * 4 + 3] = b4[3];
      }
    }

    // sim^T[j][i] = MFMA(A=k[j][dh], B=q[i][dh]); i = sub*32 + il
    bf16x8 bq0 = ldQK(qb, sub * 32 + il, kfb);        // dh 0..15 slice
    bf16x8 bq1 = ldQK(qb, sub * 32 + il, 16 + kfb);   // dh 16..31 slice
    f32x16 sim[2];
    #pragma unroll
    for (int jt = 0; jt < 2; ++jt) {
      bf16x8 ak0f = ldQK(kb, jt * 32 + il, kfb);
      bf16x8 ak1f = ldQK(kb, jt * 32 + il, 16 + kfb);
      f32x16 s = MFMA32(ak0f, bq0, fz16);
      sim[jt] = MFMA32(ak1f, bq1, s);
    }

    // in-lane softmax (32 j/lane) + 1 shfl_xor(32); normalize; pack P
    uint2 pks[2][4];
    {
      f32x16 vals[2];
      #pragma unroll
      for (int jt = 0; jt < 2; ++jt)
        #pragma unroll
        for (int r = 0; r < 16; ++r) vals[jt][r] = sim[jt][r] + bias[jt][r];
      float m = vals[0][0];
      #pragma unroll
      for (int jt = 0; jt < 2; ++jt)
        #pragma unroll
        for (int r = 0; r < 16; ++r) m = fmaxf(m, vals[jt][r]);
      m = fmaxf(m, __shfl_xor(m, 32));
      float s = 0.f;
      #pragma unroll
      for (int jt = 0; jt < 2; ++jt)
        #pragma unroll
        for (int r = 0; r < 16; ++r) {
          float pv = __expf(vals[jt][r] - m);
          vals[jt][r] = pv;
          s += pv;
        }
      s += __shfl_xor(s, 32);
      float inv = 1.0f / s;
      #pragma unroll
      for (int jt = 0; jt < 2; ++jt)
        #pragma unroll
        for (int rq = 0; rq < 4; ++rq) {
          pks[jt][rq].x = pkbf(vals[jt][rq * 4 + 0] * inv, vals[jt][rq * 4 + 1] * inv);
          pks[jt][rq].y = pkbf(vals[jt][rq * 4 + 2] * inv, vals[jt][rq * 4 + 3] * inv);
        }
    }

    __syncthreads();  // both waves done reading q/k -> P may overwrite alias

    // P write: row i = sub*32+il, j0 = jt*32 + rq*8 + hi*4, packed uint2
    {
      int i = sub * 32 + il;
      if (i < 49) {
        #pragma unroll
        for (int jt = 0; jt < 2; ++jt)
          #pragma unroll
          for (int rq = 0; rq < 4; ++rq) {
            int j0 = jt * 32 + rq * 8 + hi * 4;
            unsigned a = ((unsigned)(i * 128 + j0 * 2)) ^ SWZ_P(i);
            *(uint2*)(Pb + a) = pks[jt][rq];
          }
      }
    }

    // PV (32x32x16 swapped): out^T[dh][i]; 2 interleaved chains over j
    f32x16 oa0 = fz16, oa1 = fz16;
    #pragma unroll
    for (int ks = 0; ks < 4; ++ks) {
      int jc = ks * 16 + kfb;
      bf16x8 afv = ldVT(vt, il, jc);
      bf16x8 bfp = ldP2(Pb, sub * 32 + il, jc);
      if (ks & 1) oa1 = MFMA32(afv, bfp, oa1);
      else        oa0 = MFMA32(afv, bfp, oa0);
    }

    // store: tok = col = sub*32+il; dh = rq*8 + hi*4 (+0..3) -> f32x4
    float* ow = out + (size_t)bw * 25088 + h * 32;
    {
      int tok = sub * 32 + il;
      if (tok < 49) {
        #pragma unroll
        for (int rq = 0; rq < 4; ++rq) {
          int dh0 = rq * 8 + hi * 4;
          f32x4 vv;
          vv[0] = oa0[rq * 4 + 0] + oa1[rq * 4 + 0];
          vv[1] = oa0[rq * 4 + 1] + oa1[rq * 4 + 1];
          vv[2] = oa0[rq * 4 + 2] + oa1[rq * 4 + 2];
          vv[3] = oa0[rq * 4 + 3] + oa1[rq * 4 + 3];
          *(f32x4*)(&ow[(size_t)tok * 512 + dh0]) = vv;
        }
      }
    }
  }
}

extern "C" void kernel_launch(void* const* d_in, const int* in_sizes, int n_in,
                              void* d_out, int out_size, void* d_ws, size_t ws_size,
                              hipStream_t stream) {
  (void)in_sizes; (void)n_in; (void)out_size; (void)ws_size;
  const float* x = (const float*)d_in[0];
  const float* y = (const float*)d_in[1];
  const float* Wq = (const float*)d_in[2];
  const float* Wkv = (const float*)d_in[3];
  const float* bt = (const float*)d_in[4];
  float* out = (float*)d_out;
  char* ws = (char*)d_ws;

  prep_kernel<<<3072, 256, 0, stream>>>(Wq, Wkv, bt, ws);

  (void)hipFuncSetAttribute((const void*)attn_kernel,
                            hipFuncAttributeMaxDynamicSharedMemorySize, 141824);
  attn_kernel<<<4096, 512, 141824, stream>>>(x, y, (const char*)ws,
                                             (const float*)(ws + 1572864), out);
}